// Round 2
// baseline (3311.101 us; speedup 1.0000x reference)
//
#include <hip/hip_runtime.h>
#include <stdint.h>
#include <math.h>

// Problem dims (fixed by reference setup_inputs)
#define NN 8
#define TT 256
#define BB 4
#define DD 512
#define VV 32000
#define MM (NN*TT*BB)          // 8192 rows

// GEMM tiling
#define BM 128
#define BN 128
#define BK 8
#define VTPB 5                 // col-tiles swept per block
#define GRIDX (VV/(BN*VTPB))   // 50

// ---------- helpers ----------

// Monotone map float -> uint32 (order-preserving for all non-NaN)
__device__ __forceinline__ uint32_t fkey(float v){
  uint32_t b = __float_as_uint(v);
  return b ^ ((b & 0x80000000u) ? 0xFFFFFFFFu : 0x80000000u);
}

// Exact JAX threefry2x32 (Random123), 20 rounds.
__device__ __forceinline__ uint32_t rotl32(uint32_t x, int r){
  return (x << r) | (x >> (32 - r));
}
__device__ __forceinline__ void threefry2x32(uint32_t k0, uint32_t k1,
                                             uint32_t& x0, uint32_t& x1){
  const uint32_t ks0 = k0, ks1 = k1, ks2 = k0 ^ k1 ^ 0x1BD11BDAu;
  x0 += ks0; x1 += ks1;
  // block 0 (rot set 0), inject ks1, ks2+1
  x0 += x1; x1 = rotl32(x1,13); x1 ^= x0;
  x0 += x1; x1 = rotl32(x1,15); x1 ^= x0;
  x0 += x1; x1 = rotl32(x1,26); x1 ^= x0;
  x0 += x1; x1 = rotl32(x1, 6); x1 ^= x0;
  x0 += ks1; x1 += ks2 + 1u;
  // block 1 (rot set 1), inject ks2, ks0+2
  x0 += x1; x1 = rotl32(x1,17); x1 ^= x0;
  x0 += x1; x1 = rotl32(x1,29); x1 ^= x0;
  x0 += x1; x1 = rotl32(x1,16); x1 ^= x0;
  x0 += x1; x1 = rotl32(x1,24); x1 ^= x0;
  x0 += ks2; x1 += ks0 + 2u;
  // block 2 (rot set 0), inject ks0, ks1+3
  x0 += x1; x1 = rotl32(x1,13); x1 ^= x0;
  x0 += x1; x1 = rotl32(x1,15); x1 ^= x0;
  x0 += x1; x1 = rotl32(x1,26); x1 ^= x0;
  x0 += x1; x1 = rotl32(x1, 6); x1 ^= x0;
  x0 += ks0; x1 += ks1 + 3u;
  // block 3 (rot set 1), inject ks1, ks2+4
  x0 += x1; x1 = rotl32(x1,17); x1 ^= x0;
  x0 += x1; x1 = rotl32(x1,29); x1 ^= x0;
  x0 += x1; x1 = rotl32(x1,16); x1 ^= x0;
  x0 += x1; x1 = rotl32(x1,24); x1 ^= x0;
  x0 += ks1; x1 += ks2 + 4u;
  // block 4 (rot set 0), inject ks2, ks0+5
  x0 += x1; x1 = rotl32(x1,13); x1 ^= x0;
  x0 += x1; x1 = rotl32(x1,15); x1 ^= x0;
  x0 += x1; x1 = rotl32(x1,26); x1 ^= x0;
  x0 += x1; x1 = rotl32(x1, 6); x1 ^= x0;
  x0 += ks2; x1 += ks0 + 5u;
}

__device__ __forceinline__ float uniform_from_bits(uint32_t bits){
  return __uint_as_float((bits >> 9) | 0x3f800000u) - 1.0f;
}

// ---------- kernel 0: init packed argmax accumulators ----------
__global__ void init_kernel(unsigned long long* __restrict__ packed){
  int i = blockIdx.x * blockDim.x + threadIdx.x;
  if (i < MM) packed[i] = 0ULL;
}

// ---------- kernel 1: fused fp32 GEMM (A·W^T) + row argmax ----------
// A: [MM, DD] (block_outputs flattened), W: [VV, DD]. packed[r] accumulates
// max over (fkey(logit)<<32 | ~col)  -> argmax with first-index tie-break.
__global__ __launch_bounds__(256)
void gemm_argmax_kernel(const float* __restrict__ A,
                        const float* __restrict__ W,
                        unsigned long long* __restrict__ packed){
  __shared__ float As[BK][BM + 8];   // row stride 136 floats: 16B-aligned rows
  __shared__ float Bs[BK][BN + 8];
  __shared__ unsigned long long lmax[BM];

  const int tid   = threadIdx.x;
  const int mtile = blockIdx.y * BM;
  const int tx = tid & 15;
  const int ty = tid >> 4;
  const int lr = tid >> 1;          // 0..127: tile row loaded by this thread
  const int lc = (tid & 1) * 4;     // 0 or 4: k-subcolumn

  if (tid < BM) lmax[tid] = 0ULL;   // visible before first use (barriers below)

  for (int vt = 0; vt < VTPB; ++vt){
    const int ntile = (blockIdx.x * VTPB + vt) * BN;

    float acc[8][8];
    #pragma unroll
    for (int i = 0; i < 8; ++i)
      #pragma unroll
      for (int j = 0; j < 8; ++j) acc[i][j] = 0.0f;

    for (int k0 = 0; k0 < DD; k0 += BK){
      const float4 a4 = *(const float4*)&A[(size_t)(mtile + lr) * DD + k0 + lc];
      const float4 b4 = *(const float4*)&W[(size_t)(ntile + lr) * DD + k0 + lc];
      __syncthreads();              // previous tile fully consumed
      As[lc+0][lr] = a4.x; As[lc+1][lr] = a4.y;
      As[lc+2][lr] = a4.z; As[lc+3][lr] = a4.w;
      Bs[lc+0][lr] = b4.x; Bs[lc+1][lr] = b4.y;
      Bs[lc+2][lr] = b4.z; Bs[lc+3][lr] = b4.w;
      __syncthreads();              // tile ready

      #pragma unroll
      for (int k = 0; k < BK; ++k){
        float a[8], b[8];
        *(float4*)&a[0] = *(const float4*)&As[k][ty * 4];
        *(float4*)&a[4] = *(const float4*)&As[k][64 + ty * 4];
        *(float4*)&b[0] = *(const float4*)&Bs[k][tx * 4];
        *(float4*)&b[4] = *(const float4*)&Bs[k][64 + tx * 4];
        #pragma unroll
        for (int i = 0; i < 8; ++i)
          #pragma unroll
          for (int j = 0; j < 8; ++j)
            acc[i][j] = fmaf(a[i], b[j], acc[i][j]);
      }
    }

    // epilogue: per-thread row-wise argmax over its 8 columns -> LDS atomic
    #pragma unroll
    for (int i = 0; i < 8; ++i){
      const int mloc = (i < 4) ? (ty * 4 + i) : (64 + ty * 4 + (i - 4));
      unsigned long long best = 0ULL;
      #pragma unroll
      for (int j = 0; j < 8; ++j){
        const int col = ntile + ((j < 4) ? (tx * 4 + j) : (64 + tx * 4 + (j - 4)));
        const unsigned long long p =
            ((unsigned long long)fkey(acc[i][j]) << 32) |
            (unsigned long long)(~(uint32_t)col);
        if (p > best) best = p;
      }
      atomicMax(&lmax[mloc], best);
    }
  }

  __syncthreads();
  if (tid < BM) atomicMax(&packed[mtile + tid], lmax[tid]);
}

// ---------- kernel 2: scores[r] = sqrt(D) * dot(outputs[n,t,:], W[argmax_r]) ----------
__global__ __launch_bounds__(256)
void score_kernel(const float* __restrict__ outputs,
                  const float* __restrict__ W,
                  const unsigned long long* __restrict__ packed,
                  float* __restrict__ scores){
  const int wave = threadIdx.x >> 6;          // 0..3
  const int lane = threadIdx.x & 63;
  const int r = blockIdx.x * 4 + wave;        // row 0..8191
  const uint32_t idx = ~(uint32_t)(packed[r]);        // recover argmax col
  const int n = r >> 10;                      // r / (T*B)
  const int t = (r >> 2) & (TT - 1);
  const float* ov = outputs + ((size_t)(n * TT + t) << 9);
  const float* wv = W + (size_t)idx * DD;
  float s = 0.0f;
  #pragma unroll
  for (int j = 0; j < 8; ++j){
    const int d = lane + j * 64;
    s = fmaf(ov[d], wv[d], s);
  }
  #pragma unroll
  for (int off = 32; off > 0; off >>= 1) s += __shfl_down(s, off);
  if (lane == 0) scores[r] = s * 22.62741699796952f;  // float32(sqrt(512))
}

// ---------- kernel 3: sequential accept/reject scan + mask scatter ----------
__global__ __launch_bounds__(256)
void scan_kernel(const float* __restrict__ scores, float* __restrict__ mask_out){
  __shared__ float sc[MM];          // 32 KB
  __shared__ float uu[TT * NN];     // 8 KB of precomputed uniforms

  const int tid = threadIdx.x;

  for (int i = tid; i < MM; i += 256){
    mask_out[i] = 0.0f;             // d_out is poisoned each call
    sc[i] = scores[i];
  }

  // Uniforms for step t = tid, PARTITIONABLE threefry (JAX >= 0.4.36 default):
  //   key' = threefry2x32((0,42), (0,t))            [fold_in, unchanged]
  //   per element n of the shape-(8,) draw: 64-bit counter (hi=0, lo=n)
  //   (o0,o1) = threefry2x32(key', (0, n)); bits = o0 ^ o1
  //   u = bitcast((bits>>9)|0x3f800000) - 1
  {
    const int t = tid;
    uint32_t k0 = 0u, k1 = (uint32_t)t;
    threefry2x32(0u, 42u, k0, k1);          // fold_in(key(42), t)
    #pragma unroll
    for (int n = 0; n < NN; ++n){
      uint32_t x0 = 0u, x1 = (uint32_t)n;
      threefry2x32(k0, k1, x0, x1);
      uu[t * NN + n] = uniform_from_bits(x0 ^ x1);
    }
  }
  __syncthreads();

  if (tid < NN){
    const int n = tid;
    int x = 0, y = 0;
    for (int t = 0; t < TT; ++t){
      const int idx0 = x * BB + y;
      mask_out[n * (TT * BB) + idx0] = 1.0f;      // record pre-update index
      const float scx0 = sc[n * (TT * BB) + idx0];
      const float scx1 = sc[n * (TT * BB) + t * BB];
      const float prob = 1.0f / (1.0f + expf(-((scx0 - scx1) / 10.0f)));
      int accept = (uu[t * NN + n] < prob) ? 1 : 0;
      if (y + accept >= BB) accept = 0;           // m = (y1 < B)
      y = (y + accept) * accept;
      x = x * accept + (t + 1) * (1 - accept);
    }
  }
}

// ---------- launcher ----------
extern "C" void kernel_launch(void* const* d_in, const int* in_sizes, int n_in,
                              void* d_out, int out_size, void* d_ws, size_t ws_size,
                              hipStream_t stream){
  const float* outputs       = (const float*)d_in[0];   // [8,256,512]
  const float* block_outputs = (const float*)d_in[1];   // [8,256,4,512]
  const float* W             = (const float*)d_in[2];   // [32000,512]

  unsigned long long* packed = (unsigned long long*)d_ws;           // 64 KB
  float* scores = (float*)((char*)d_ws + (size_t)MM * sizeof(unsigned long long));

  init_kernel<<<(MM + 255) / 256, 256, 0, stream>>>(packed);
  gemm_argmax_kernel<<<dim3(GRIDX, MM / BM), 256, 0, stream>>>(block_outputs, W, packed);
  score_kernel<<<MM / 4, 256, 0, stream>>>(outputs, W, packed, scores);
  scan_kernel<<<1, 256, 0, stream>>>(scores, (float*)d_out);
}

// Round 3
// 1241.489 us; speedup vs baseline: 2.6670x; 2.6670x over previous
//
#include <hip/hip_runtime.h>
#include <stdint.h>
#include <math.h>

// Problem dims (fixed by reference setup_inputs)
#define NN 8
#define TT 256
#define BB 4
#define DD 512
#define VV 32000
#define MM (NN*TT*BB)          // 8192 rows

// MFMA GEMM tiling
#define TM 128
#define TN 128
#define BK 32
#define VT 5                   // n-tiles swept per block
#define GX (VV/(TN*VT))        // 50

typedef _Float16 half8 __attribute__((ext_vector_type(8)));
typedef float    f32x4 __attribute__((ext_vector_type(4)));

#define MFMA16(a,b,c) __builtin_amdgcn_mfma_f32_16x16x32_f16((a),(b),(c),0,0,0)

// ---------- helpers ----------

// Monotone map float -> uint32 (order-preserving for all non-NaN)
__device__ __forceinline__ uint32_t fkey(float v){
  uint32_t b = __float_as_uint(v);
  return b ^ ((b & 0x80000000u) ? 0xFFFFFFFFu : 0x80000000u);
}

// Exact JAX threefry2x32 (Random123), 20 rounds.
__device__ __forceinline__ uint32_t rotl32(uint32_t x, int r){
  return (x << r) | (x >> (32 - r));
}
__device__ __forceinline__ void threefry2x32(uint32_t k0, uint32_t k1,
                                             uint32_t& x0, uint32_t& x1){
  const uint32_t ks0 = k0, ks1 = k1, ks2 = k0 ^ k1 ^ 0x1BD11BDAu;
  x0 += ks0; x1 += ks1;
  x0 += x1; x1 = rotl32(x1,13); x1 ^= x0;
  x0 += x1; x1 = rotl32(x1,15); x1 ^= x0;
  x0 += x1; x1 = rotl32(x1,26); x1 ^= x0;
  x0 += x1; x1 = rotl32(x1, 6); x1 ^= x0;
  x0 += ks1; x1 += ks2 + 1u;
  x0 += x1; x1 = rotl32(x1,17); x1 ^= x0;
  x0 += x1; x1 = rotl32(x1,29); x1 ^= x0;
  x0 += x1; x1 = rotl32(x1,16); x1 ^= x0;
  x0 += x1; x1 = rotl32(x1,24); x1 ^= x0;
  x0 += ks2; x1 += ks0 + 2u;
  x0 += x1; x1 = rotl32(x1,13); x1 ^= x0;
  x0 += x1; x1 = rotl32(x1,15); x1 ^= x0;
  x0 += x1; x1 = rotl32(x1,26); x1 ^= x0;
  x0 += x1; x1 = rotl32(x1, 6); x1 ^= x0;
  x0 += ks0; x1 += ks1 + 3u;
  x0 += x1; x1 = rotl32(x1,17); x1 ^= x0;
  x0 += x1; x1 = rotl32(x1,29); x1 ^= x0;
  x0 += x1; x1 = rotl32(x1,16); x1 ^= x0;
  x0 += x1; x1 = rotl32(x1,24); x1 ^= x0;
  x0 += ks1; x1 += ks2 + 4u;
  x0 += x1; x1 = rotl32(x1,13); x1 ^= x0;
  x0 += x1; x1 = rotl32(x1,15); x1 ^= x0;
  x0 += x1; x1 = rotl32(x1,26); x1 ^= x0;
  x0 += x1; x1 = rotl32(x1, 6); x1 ^= x0;
  x0 += ks2; x1 += ks0 + 5u;
}

__device__ __forceinline__ float uniform_from_bits(uint32_t bits){
  return __uint_as_float((bits >> 9) | 0x3f800000u) - 1.0f;
}

// split x*scale into f16 hi + f16 lo where lo = (x*scale - hi)*4096
__device__ __forceinline__ void cvt8(const float4& p, const float4& q, float scale,
                                     half8& h, half8& l){
  float v[8] = {p.x,p.y,p.z,p.w,q.x,q.y,q.z,q.w};
  #pragma unroll
  for (int j = 0; j < 8; ++j){
    const float s = v[j] * scale;
    const _Float16 hh = (_Float16)s;
    h[j] = hh;
    l[j] = (_Float16)((s - (float)hh) * 4096.0f);
  }
}

// ---------- kernel 0: init packed argmax accumulators ----------
__global__ void init_kernel(unsigned long long* __restrict__ packed){
  int i = blockIdx.x * blockDim.x + threadIdx.x;
  if (i < MM) packed[i] = 0ULL;
}

// ---------- kernel 1: split-f16 MFMA GEMM (A.W^T) + fused row argmax ----------
// A:[MM,DD] fp32, W:[VV,DD] fp32. Pre-scale A by 2^12, W by 2^14 (keeps f16
// hi-parts normal; argmax is invariant under positive scaling). Per element:
// a = a_hi + a_lo/4096 (f16 pair). acc1 = ah.bh, acc2 = ah.bl + al.bh;
// scaled_logit = acc1 + acc2/4096. Row argmax via packed (fkey<<32 | ~col).
__global__ __launch_bounds__(256, 2)
void gemm_argmax_kernel(const float* __restrict__ A,
                        const float* __restrict__ W,
                        unsigned long long* __restrict__ packed){
  __shared__ __align__(16) _Float16 Ah[TM][40];   // +8 pad: 2-way-free banks
  __shared__ __align__(16) _Float16 Al[TM][40];
  __shared__ __align__(16) _Float16 Bh[TN][40];
  __shared__ __align__(16) _Float16 Bl[TN][40];
  __shared__ unsigned long long lmax[TM];

  const int tid   = threadIdx.x;
  const int mtile = blockIdx.y * TM;
  const int wid    = tid >> 6;
  const int lane   = tid & 63;
  const int lm     = lane & 15;            // row/col within 16-tile
  const int lk     = lane >> 4;            // k-chunk 0..3 (8 f16 each)
  const int wave_m = (wid & 1) * 64;
  const int wave_n = (wid >> 1) * 64;

  const int srow = tid >> 2;               // 0..63: staging row
  const int skc  = (tid & 3) * 8;          // 0/8/16/24: staging k-col

  if (tid < TM) lmax[tid] = 0ULL;

  for (int vt = 0; vt < VT; ++vt){
    const int ntile = (blockIdx.x * VT + vt) * TN;

    f32x4 acc1[4][4], acc2[4][4];
    #pragma unroll
    for (int i = 0; i < 4; ++i)
      #pragma unroll
      for (int j = 0; j < 4; ++j){ acc1[i][j] = (f32x4)0.0f; acc2[i][j] = (f32x4)0.0f; }

    for (int k0 = 0; k0 < DD; k0 += BK){
      // global fp32 staging loads (2 rows x 8 cols each for A and B)
      const float* pa0 = &A[(size_t)(mtile + srow     ) * DD + k0 + skc];
      const float* pa1 = &A[(size_t)(mtile + srow + 64) * DD + k0 + skc];
      const float* pb0 = &W[(size_t)(ntile + srow     ) * DD + k0 + skc];
      const float* pb1 = &W[(size_t)(ntile + srow + 64) * DD + k0 + skc];
      const float4 a00 = *(const float4*)(pa0), a01 = *(const float4*)(pa0 + 4);
      const float4 a10 = *(const float4*)(pa1), a11 = *(const float4*)(pa1 + 4);
      const float4 b00 = *(const float4*)(pb0), b01 = *(const float4*)(pb0 + 4);
      const float4 b10 = *(const float4*)(pb1), b11 = *(const float4*)(pb1 + 4);

      __syncthreads();                     // previous chunk's LDS consumed

      half8 h, l;
      cvt8(a00, a01, 4096.0f,  h, l);      // A * 2^12
      *(half8*)&Ah[srow     ][skc] = h; *(half8*)&Al[srow     ][skc] = l;
      cvt8(a10, a11, 4096.0f,  h, l);
      *(half8*)&Ah[srow + 64][skc] = h; *(half8*)&Al[srow + 64][skc] = l;
      cvt8(b00, b01, 16384.0f, h, l);      // W * 2^14
      *(half8*)&Bh[srow     ][skc] = h; *(half8*)&Bl[srow     ][skc] = l;
      cvt8(b10, b11, 16384.0f, h, l);
      *(half8*)&Bh[srow + 64][skc] = h; *(half8*)&Bl[srow + 64][skc] = l;

      __syncthreads();                     // tile ready

      half8 ah[4], al[4], bh[4], bl[4];
      #pragma unroll
      for (int ti = 0; ti < 4; ++ti){
        const int r = wave_m + ti * 16 + lm;
        ah[ti] = *(const half8*)&Ah[r][lk * 8];
        al[ti] = *(const half8*)&Al[r][lk * 8];
      }
      #pragma unroll
      for (int tj = 0; tj < 4; ++tj){
        const int r = wave_n + tj * 16 + lm;
        bh[tj] = *(const half8*)&Bh[r][lk * 8];
        bl[tj] = *(const half8*)&Bl[r][lk * 8];
      }
      #pragma unroll
      for (int ti = 0; ti < 4; ++ti)
        #pragma unroll
        for (int tj = 0; tj < 4; ++tj){
          acc1[ti][tj] = MFMA16(ah[ti], bh[tj], acc1[ti][tj]);
          acc2[ti][tj] = MFMA16(ah[ti], bl[tj], acc2[ti][tj]);
          acc2[ti][tj] = MFMA16(al[ti], bh[tj], acc2[ti][tj]);
        }
    }

    // epilogue: C/D layout col=lane&15, row=(lane>>4)*4+reg (m89-verified)
    #pragma unroll
    for (int ti = 0; ti < 4; ++ti){
      #pragma unroll
      for (int v = 0; v < 4; ++v){
        const int mloc = wave_m + ti * 16 + lk * 4 + v;
        unsigned long long best = 0ULL;
        #pragma unroll
        for (int tj = 0; tj < 4; ++tj){
          const int col = ntile + wave_n + tj * 16 + lm;
          const float lg = acc1[ti][tj][v] + acc2[ti][tj][v] * (1.0f/4096.0f);
          const unsigned long long p =
              ((unsigned long long)fkey(lg) << 32) |
              (unsigned long long)(~(uint32_t)col);
          if (p > best) best = p;
        }
        atomicMax(&lmax[mloc], best);
      }
    }
  }

  __syncthreads();
  if (tid < TM) atomicMax(&packed[mtile + tid], lmax[tid]);
}

// ---------- kernel 2: scores[r] = sqrt(D) * dot(outputs[n,t,:], W[argmax_r]) ----------
__global__ __launch_bounds__(256)
void score_kernel(const float* __restrict__ outputs,
                  const float* __restrict__ W,
                  const unsigned long long* __restrict__ packed,
                  float* __restrict__ scores){
  const int wave = threadIdx.x >> 6;          // 0..3
  const int lane = threadIdx.x & 63;
  const int r = blockIdx.x * 4 + wave;        // row 0..8191
  const uint32_t idx = ~(uint32_t)(packed[r]);        // recover argmax col
  const int n = r >> 10;                      // r / (T*B)
  const int t = (r >> 2) & (TT - 1);
  const float* ov = outputs + ((size_t)(n * TT + t) << 9);
  const float* wv = W + (size_t)idx * DD;
  float s = 0.0f;
  #pragma unroll
  for (int j = 0; j < 8; ++j){
    const int d = lane + j * 64;
    s = fmaf(ov[d], wv[d], s);
  }
  #pragma unroll
  for (int off = 32; off > 0; off >>= 1) s += __shfl_down(s, off);
  if (lane == 0) scores[r] = s * 22.62741699796952f;  // float32(sqrt(512))
}

// ---------- kernel 3: sequential accept/reject scan + mask scatter ----------
__global__ __launch_bounds__(256)
void scan_kernel(const float* __restrict__ scores, float* __restrict__ mask_out){
  __shared__ float sc[MM];          // 32 KB
  __shared__ float uu[TT * NN];     // 8 KB of precomputed uniforms

  const int tid = threadIdx.x;

  for (int i = tid; i < MM; i += 256){
    mask_out[i] = 0.0f;             // d_out is poisoned each call
    sc[i] = scores[i];
  }

  // Uniforms for step t = tid, PARTITIONABLE threefry (JAX >= 0.4.36 default):
  //   key' = threefry2x32((0,42), (0,t)); element n: (o0,o1)=threefry2x32(key',(0,n))
  //   bits = o0 ^ o1; u = bitcast((bits>>9)|0x3f800000) - 1
  {
    const int t = tid;
    uint32_t k0 = 0u, k1 = (uint32_t)t;
    threefry2x32(0u, 42u, k0, k1);          // fold_in(key(42), t)
    #pragma unroll
    for (int n = 0; n < NN; ++n){
      uint32_t x0 = 0u, x1 = (uint32_t)n;
      threefry2x32(k0, k1, x0, x1);
      uu[t * NN + n] = uniform_from_bits(x0 ^ x1);
    }
  }
  __syncthreads();

  if (tid < NN){
    const int n = tid;
    int x = 0, y = 0;
    for (int t = 0; t < TT; ++t){
      const int idx0 = x * BB + y;
      mask_out[n * (TT * BB) + idx0] = 1.0f;      // record pre-update index
      const float scx0 = sc[n * (TT * BB) + idx0];
      const float scx1 = sc[n * (TT * BB) + t * BB];
      const float prob = 1.0f / (1.0f + expf(-((scx0 - scx1) / 10.0f)));
      int accept = (uu[t * NN + n] < prob) ? 1 : 0;
      if (y + accept >= BB) accept = 0;           // m = (y1 < B)
      y = (y + accept) * accept;
      x = x * accept + (t + 1) * (1 - accept);
    }
  }
}

// ---------- launcher ----------
extern "C" void kernel_launch(void* const* d_in, const int* in_sizes, int n_in,
                              void* d_out, int out_size, void* d_ws, size_t ws_size,
                              hipStream_t stream){
  const float* outputs       = (const float*)d_in[0];   // [8,256,512]
  const float* block_outputs = (const float*)d_in[1];   // [8,256,4,512]
  const float* W             = (const float*)d_in[2];   // [32000,512]

  unsigned long long* packed = (unsigned long long*)d_ws;           // 64 KB
  float* scores = (float*)((char*)d_ws + (size_t)MM * sizeof(unsigned long long));

  init_kernel<<<(MM + 255) / 256, 256, 0, stream>>>(packed);
  gemm_argmax_kernel<<<dim3(GX, MM / TM), 256, 0, stream>>>(block_outputs, W, packed);
  score_kernel<<<MM / 4, 256, 0, stream>>>(outputs, W, packed, scores);
  scan_kernel<<<1, 256, 0, stream>>>(scores, (float*)d_out);
}